// Round 12
// baseline (51.861 us; speedup 1.0000x reference)
//
#include <hip/hip_runtime.h>
#include <math.h>

// Problem constants (from reference): B=65536, N=128, A=32, T=64
#define N_ATOMS  128
#define A_ALIGN  32
#define T_TRAIN  64
#define ROWF     (N_ATOMS*3)   // 384 floats per row
#define R4       (ROWF/4)      // 96 float4 per row
#define BPBLK    32            // rows per block (4 waves x 8 rows)
#define PPW      4             // pairs per wave

// One cyclic-Jacobi rotation on symmetric 3x3 Am, accumulating into Vm.
template<int p, int q, int r>
__device__ __forceinline__ void jrot(float Am[3][3], float Vm[3][3])
{
    float apq = Am[p][q];
    float app = Am[p][p];
    float aqq = Am[q][q];
    float tau = (aqq - app) / (2.0f * apq);
    float tt  = 1.0f / (fabsf(tau) + sqrtf(1.0f + tau * tau));
    float t   = copysignf(tt, tau);
    t = (fabsf(apq) > 1e-20f) ? t : 0.0f;
    float c = 1.0f / sqrtf(1.0f + t * t);
    float s = t * c;
    float arp = Am[r][p], arq = Am[r][q];
    float nrp = c * arp - s * arq;
    float nrq = s * arp + c * arq;
    Am[r][p] = nrp; Am[p][r] = nrp;
    Am[r][q] = nrq; Am[q][r] = nrq;
    Am[p][p] = app - t * apq;
    Am[q][q] = aqq + t * apq;
    Am[p][q] = 0.0f; Am[q][p] = 0.0f;
#pragma unroll
    for (int k = 0; k < 3; ++k) {
        float vp = Vm[k][p], vq = Vm[k][q];
        Vm[k][p] = c * vp - s * vq;
        Vm[k][q] = s * vp + c * vq;
    }
}

__device__ __forceinline__ float redu32(float v)
{
#pragma unroll
    for (int m = 16; m >= 1; m >>= 1)
        v += __shfl_xor(v, m, 32);
    return v;
}

// Fully wave-autonomous, ZERO-barrier kernel. Each wave owns 8 rows:
// P1: stream 4 pairs (coalesced float4 -> wave slice -> butterfly reduce),
//     train atoms kept in registers, P dropped into wave-local Pw.
// P2: lanes 0..7 run one Jacobi chain each (all 4 waves chain concurrently).
// P3: register transform + float3 stores.
// Cross-lane LDS visibility within a wave needs no __syncthreads (in-order).
__global__ __launch_bounds__(256)
void kabsch_wave_kernel(const float* __restrict__ traj,
                        const float* __restrict__ ref_x,
                        const int*   __restrict__ align_idx,
                        const int*   __restrict__ train_idx,
                        float*       __restrict__ out,
                        int B)
{
    __shared__ float slice[4][2 * ROWF];   // 12288 B, per-wave staging
    __shared__ float Pw[4][8][12];         // 1536 B, per-wave P then R

    const int tid = threadIdx.x;
    const int w  = tid >> 6;               // wave in block
    const int l  = tid & 63;               // lane
    const int h  = l >> 5;                 // row within pair
    const int tp = l & 31;                 // atom / train slot

    const long long wrow0 = (long long)blockIdx.x * BPBLK + w * (PPW * 2);

    // per-lane constants
    const int   ia  = align_idx[tp];
    const float rx  = ref_x[tp*3+0], ry = ref_x[tp*3+1], rz = ref_x[tp*3+2];
    const int   ti0 = train_idx[tp];
    const int   ti1 = train_idx[tp + 32];

    const float4* __restrict__ g4 = (const float4*)traj;
    const long long maxf4 = (long long)B * R4;
    float4* s4 = (float4*)slice[w];
    const float* __restrict__ rb = &slice[w][h * ROWF];

    // loop-invariant ref column sums
    const float rs0 = redu32(rx), rs1 = redu32(ry), rs2 = redu32(rz);

    // train atoms carried P1 -> P3 (static-indexed via full unroll)
    float t0x[PPW], t0y[PPW], t0z[PPW];
    float t1x[PPW], t1y[PPW], t1z[PPW];

    // ---------------- Phase 1: covariance + train extraction ----------------
#pragma unroll
    for (int it = 0; it < PPW; ++it) {
        const long long b = wrow0 + it * 2;
        if (b < B) {                                // wave-uniform
            long long fb = b * R4;
            long long i0 = fb + l;        if (i0 >= maxf4) i0 = maxf4 - 1;
            long long i1 = fb + 64 + l;   if (i1 >= maxf4) i1 = maxf4 - 1;
            long long i2 = fb + 128 + l;  if (i2 >= maxf4) i2 = maxf4 - 1;
            float4 v0 = g4[i0];
            float4 v1 = g4[i1];
            float4 v2 = g4[i2];
            s4[l]       = v0;
            s4[64 + l]  = v1;
            s4[128 + l] = v2;
            // same-wave producer/consumer: LDS ops in-order per wave

            float px = rb[ia*3+0], py = rb[ia*3+1], pz = rb[ia*3+2];
            t0x[it] = rb[ti0*3+0]; t0y[it] = rb[ti0*3+1]; t0z[it] = rb[ti0*3+2];
            t1x[it] = rb[ti1*3+0]; t1y[it] = rb[ti1*3+1]; t1z[it] = rb[ti1*3+2];

            float S00 = redu32(px*rx), S01 = redu32(px*ry), S02 = redu32(px*rz);
            float S10 = redu32(py*rx), S11 = redu32(py*ry), S12 = redu32(py*rz);
            float S20 = redu32(pz*rx), S21 = redu32(pz*ry), S22 = redu32(pz*rz);
            float xs0 = redu32(px), xs1 = redu32(py), xs2 = redu32(pz);

            if (tp == 0 && (b + h) < B) {
                const float inv_a = 1.0f / (float)A_ALIGN;
                float c0 = xs0*inv_a, c1 = xs1*inv_a, c2 = xs2*inv_a;
                float4* o4 = (float4*)Pw[w][it*2 + h];
                o4[0] = make_float4(S00 - c0*rs0, S01 - c0*rs1, S02 - c0*rs2,
                                    S10 - c1*rs0);
                o4[1] = make_float4(S11 - c1*rs1, S12 - c1*rs2, S20 - c2*rs0,
                                    S21 - c2*rs1);
                o4[2] = make_float4(S22 - c2*rs2, c0, c1, c2);
            }
        }
    }

    // ---------------- Phase 2: chain, lanes 0..7 of EVERY wave ---------------
    if (l < 8 && (wrow0 + l) < B) {
        float4* w4 = (float4*)Pw[w][l];
        float4 q0 = w4[0], q1 = w4[1], q2 = w4[2];
        float P00=q0.x, P01=q0.y, P02=q0.z, P10=q0.w;
        float P11=q1.x, P12=q1.y, P20=q1.z, P21=q1.w;
        float P22=q2.x, c0=q2.y, c1=q2.z, c2=q2.w;

        float Am[3][3], Vm[3][3];
        Am[0][0] = P00*P00 + P10*P10 + P20*P20;
        Am[0][1] = P00*P01 + P10*P11 + P20*P21;
        Am[0][2] = P00*P02 + P10*P12 + P20*P22;
        Am[1][1] = P01*P01 + P11*P11 + P21*P21;
        Am[1][2] = P01*P02 + P11*P12 + P21*P22;
        Am[2][2] = P02*P02 + P12*P12 + P22*P22;
        Am[1][0]=Am[0][1]; Am[2][0]=Am[0][2]; Am[2][1]=Am[1][2];
        Vm[0][0]=1.f; Vm[0][1]=0.f; Vm[0][2]=0.f;
        Vm[1][0]=0.f; Vm[1][1]=1.f; Vm[1][2]=0.f;
        Vm[2][0]=0.f; Vm[2][1]=0.f; Vm[2][2]=1.f;
#pragma unroll
        for (int sw = 0; sw < 6; ++sw) {
            jrot<0,1,2>(Am, Vm);
            jrot<0,2,1>(Am, Vm);
            jrot<1,2,0>(Am, Vm);
        }

        float l0 = Am[0][0], l1 = Am[1][1], l2 = Am[2][2];
        float v0x=Vm[0][0], v0y=Vm[1][0], v0z=Vm[2][0];
        float v1x=Vm[0][1], v1y=Vm[1][1], v1z=Vm[2][1];
        if (l0 < l1) { float t; t=l0;l0=l1;l1=t;
                       t=v0x;v0x=v1x;v1x=t; t=v0y;v0y=v1y;v1y=t; t=v0z;v0z=v1z;v1z=t; }
        { float v2x=Vm[0][2], v2y=Vm[1][2], v2z=Vm[2][2];
          if (l0 < l2) { float t; t=l0;l0=l2;l2=t;
                         t=v0x;v0x=v2x;v2x=t; t=v0y;v0y=v2y;v2y=t; t=v0z;v0z=v2z;v2z=t; }
          if (l1 < l2) { float t; t=l1;l1=l2;l2=t;
                         t=v1x;v1x=v2x;v2x=t; t=v1y;v1y=v2y;v2y=t; t=v1z;v1z=v2z;v2z=t; }
        }
        float v2x = v0y*v1z - v0z*v1y;
        float v2y = v0z*v1x - v0x*v1z;
        float v2z = v0x*v1y - v0y*v1x;
        float w0x = P00*v0x + P01*v0y + P02*v0z;
        float w0y = P10*v0x + P11*v0y + P12*v0z;
        float w0z = P20*v0x + P21*v0y + P22*v0z;
        float i0 = 1.0f / sqrtf(fmaxf(w0x*w0x+w0y*w0y+w0z*w0z, 1e-30f));
        float u0x=w0x*i0, u0y=w0y*i0, u0z=w0z*i0;
        float w1x = P00*v1x + P01*v1y + P02*v1z;
        float w1y = P10*v1x + P11*v1y + P12*v1z;
        float w1z = P20*v1x + P21*v1y + P22*v1z;
        float d01 = u0x*w1x + u0y*w1y + u0z*w1z;
        w1x -= d01*u0x; w1y -= d01*u0y; w1z -= d01*u0z;
        float i1 = 1.0f / sqrtf(fmaxf(w1x*w1x+w1y*w1y+w1z*w1z, 1e-30f));
        float u1x=w1x*i1, u1y=w1y*i1, u1z=w1z*i1;
        float u2x = u0y*u1z - u0z*u1y;
        float u2y = u0z*u1x - u0x*u1z;
        float u2z = u0x*u1y - u0y*u1x;

        w4[0] = make_float4(u0x*v0x + u1x*v1x + u2x*v2x,
                            u0x*v0y + u1x*v1y + u2x*v2y,
                            u0x*v0z + u1x*v1z + u2x*v2z,
                            u0y*v0x + u1y*v1x + u2y*v2x);
        w4[1] = make_float4(u0y*v0y + u1y*v1y + u2y*v2y,
                            u0y*v0z + u1y*v1z + u2y*v2z,
                            u0z*v0x + u1z*v1x + u2z*v2x,
                            u0z*v0y + u1z*v1y + u2z*v2y);
        w4[2] = make_float4(u0z*v0z + u1z*v1z + u2z*v2z, c0, c1, c2);
    }
    // no barrier: chain writes and P3 reads are same-wave, LDS in-order

    // ---------------- Phase 3: register transform + float3 stores -----------
#pragma unroll
    for (int it = 0; it < PPW; ++it) {
        const long long brow = wrow0 + it * 2 + h;
        if (brow < B) {
            const float4* r4p = (const float4*)Pw[w][it*2 + h]; // bcast/half-wave
            float4 q0 = r4p[0], q1 = r4p[1], q2 = r4p[2];
            float R00=q0.x, R01=q0.y, R02=q0.z, R10=q0.w;
            float R11=q1.x, R12=q1.y, R20=q1.z, R21=q1.w;
            float R22=q2.x, c0=q2.y, c1=q2.z, c2=q2.w;
            {
                float x0 = t0x[it]-c0, x1 = t0y[it]-c1, x2 = t0z[it]-c2;
                float3 y;
                y.x = x0*R00 + x1*R10 + x2*R20;
                y.y = x0*R01 + x1*R11 + x2*R21;
                y.z = x0*R02 + x1*R12 + x2*R22;
                *(float3*)(out + (brow * T_TRAIN + tp) * 3) = y;
            }
            {
                float x0 = t1x[it]-c0, x1 = t1y[it]-c1, x2 = t1z[it]-c2;
                float3 y;
                y.x = x0*R00 + x1*R10 + x2*R20;
                y.y = x0*R01 + x1*R11 + x2*R21;
                y.z = x0*R02 + x1*R12 + x2*R22;
                *(float3*)(out + (brow * T_TRAIN + tp + 32) * 3) = y;
            }
        }
    }
}

extern "C" void kernel_launch(void* const* d_in, const int* in_sizes, int n_in,
                              void* d_out, int out_size, void* d_ws, size_t ws_size,
                              hipStream_t stream)
{
    const float* traj      = (const float*)d_in[0];
    const float* ref_x     = (const float*)d_in[1];
    const int*   align_idx = (const int*)d_in[2];
    const int*   train_idx = (const int*)d_in[3];
    float* out = (float*)d_out;
    int B = in_sizes[0] / (N_ATOMS * 3);

    int nblk = (B + BPBLK - 1) / BPBLK;
    kabsch_wave_kernel<<<dim3(nblk), dim3(256), 0, stream>>>(
        traj, ref_x, align_idx, train_idx, out, B);
}

// Round 13
// 43.555 us; speedup vs baseline: 1.1907x; 1.1907x over previous
//
#include <hip/hip_runtime.h>
#include <math.h>

// Problem constants (from reference): B=65536, N=128, A=32, T=64
#define N_ATOMS  128
#define A_ALIGN  32
#define T_TRAIN  64
#define ROWF     (N_ATOMS*3)   // 384 floats per row
#define R4       (ROWF/4)      // 96 float4 per row
#define BPBLK    64            // rows per block (4 waves x 8 pairs x 2 rows)
#define PPW      8             // pairs per wave
#define ASTRIDE  97            // Abuf row stride (floats): 97 mod 32 = 1 -> conflict-free

// One cyclic-Jacobi rotation on symmetric 3x3 Am, accumulating into Vm.
template<int p, int q, int r>
__device__ __forceinline__ void jrot(float Am[3][3], float Vm[3][3])
{
    float apq = Am[p][q];
    float app = Am[p][p];
    float aqq = Am[q][q];
    float tau = (aqq - app) / (2.0f * apq);
    float tt  = 1.0f / (fabsf(tau) + sqrtf(1.0f + tau * tau));
    float t   = copysignf(tt, tau);
    t = (fabsf(apq) > 1e-20f) ? t : 0.0f;
    float c = 1.0f / sqrtf(1.0f + t * t);
    float s = t * c;
    float arp = Am[r][p], arq = Am[r][q];
    float nrp = c * arp - s * arq;
    float nrq = s * arp + c * arq;
    Am[r][p] = nrp; Am[p][r] = nrp;
    Am[r][q] = nrq; Am[q][r] = nrq;
    Am[p][p] = app - t * apq;
    Am[q][q] = aqq + t * apq;
    Am[p][q] = 0.0f; Am[q][p] = 0.0f;
#pragma unroll
    for (int k = 0; k < 3; ++k) {
        float vp = Vm[k][p], vq = Vm[k][q];
        Vm[k][p] = c * vp - s * vq;
        Vm[k][q] = s * vp + c * vq;
    }
}

// Block = 64 rows.
// P1 (all 4 waves): stream pairs coalesced -> wave slice; extract align atoms
//     -> compact Abuf (LDS), train atoms -> registers. NO cross-lane reduce.
// P2 (wave blockIdx&3): thread-per-row cov (per-thread FMA from Abuf) +
//     Jacobi chain at FULL 64-lane efficiency -> Pbuf (R + centroid).
// P3 (all 4 waves): register transform + float3 stores (line-dense).
// LDS: Abuf | {slices (P1) alias Pbuf (P2+)} = 37 KB -> 4 blocks/CU.
__global__ __launch_bounds__(256, 4)
void kabsch_block_kernel(const float* __restrict__ traj,
                         const float* __restrict__ ref_x,
                         const int*   __restrict__ align_idx,
                         const int*   __restrict__ train_idx,
                         float*       __restrict__ out,
                         int B)
{
    __shared__ float Abuf[BPBLK * ASTRIDE];          // 24832 B
    __shared__ float shr2[4 * 2 * ROWF];             // 12288 B: slices, then Pbuf
    float* const slice_w = &shr2[(threadIdx.x >> 6) * (2 * ROWF)];
    float* const Pbuf    = shr2;                     // aliased after barrier 1

    const int tid = threadIdx.x;
    const int w  = tid >> 6;               // wave in block
    const int l  = tid & 63;               // lane
    const int h  = l >> 5;                 // row within pair
    const int tp = l & 31;                 // atom / train slot

    const long long bbase = (long long)blockIdx.x * BPBLK;
    const long long wrow0 = bbase + w * (PPW * 2);

    // per-lane constants
    const int ia  = align_idx[tp];
    const int ti0 = train_idx[tp];
    const int ti1 = train_idx[tp + 32];

    const float4* __restrict__ g4 = (const float4*)traj;
    const long long maxf4 = (long long)B * R4;
    float4* s4 = (float4*)slice_w;
    const float* __restrict__ rb = slice_w + h * ROWF;

    // train atoms carried P1 -> P3 (static-indexed via full unroll)
    float t0x[PPW], t0y[PPW], t0z[PPW];
    float t1x[PPW], t1y[PPW], t1z[PPW];

    // ---------------- Phase 1: stage + extract ----------------
#pragma unroll
    for (int it = 0; it < PPW; ++it) {
        const long long b = wrow0 + it * 2;
        if (b < B) {                                // wave-uniform
            long long fb = b * R4;
            long long i0 = fb + l;        if (i0 >= maxf4) i0 = maxf4 - 1;
            long long i1 = fb + 64 + l;   if (i1 >= maxf4) i1 = maxf4 - 1;
            long long i2 = fb + 128 + l;  if (i2 >= maxf4) i2 = maxf4 - 1;
            float4 v0 = g4[i0];
            float4 v1 = g4[i1];
            float4 v2 = g4[i2];
            s4[l]       = v0;
            s4[64 + l]  = v1;
            s4[128 + l] = v2;
            // same-wave producer/consumer: LDS in-order per wave

            // extract align atom tp of row h -> Abuf[rl]
            const int rl = w * (PPW * 2) + it * 2 + h;     // local row 0..63
            float* ab = &Abuf[rl * ASTRIDE + tp * 3];
            ab[0] = rb[ia*3+0];
            ab[1] = rb[ia*3+1];
            ab[2] = rb[ia*3+2];

            // extract this lane's 2 train atoms of row h -> registers
            t0x[it] = rb[ti0*3+0]; t0y[it] = rb[ti0*3+1]; t0z[it] = rb[ti0*3+2];
            t1x[it] = rb[ti1*3+0]; t1y[it] = rb[ti1*3+1]; t1z[it] = rb[ti1*3+2];
        }
    }
    __syncthreads();   // Abuf complete; slices dead from here (Pbuf aliases)

    // ---------------- Phase 2: cov + chain, ONE wave, full 64 lanes ---------
    if (w == (blockIdx.x & 3) && (bbase + l) < B) {
        const float* __restrict__ ar = &Abuf[l * ASTRIDE];

        float S00=0,S01=0,S02=0,S10=0,S11=0,S12=0,S20=0,S21=0,S22=0;
        float xs0=0,xs1=0,xs2=0, rs0=0,rs1=0,rs2=0;
#pragma unroll
        for (int a = 0; a < A_ALIGN; ++a) {
            float px = ar[a*3+0], py = ar[a*3+1], pz = ar[a*3+2];
            float rx = ref_x[a*3+0], ry = ref_x[a*3+1], rz = ref_x[a*3+2]; // uniform
            S00 += px*rx; S01 += px*ry; S02 += px*rz;
            S10 += py*rx; S11 += py*ry; S12 += py*rz;
            S20 += pz*rx; S21 += pz*ry; S22 += pz*rz;
            xs0 += px; xs1 += py; xs2 += pz;
            rs0 += rx; rs1 += ry; rs2 += rz;
        }
        const float inv_a = 1.0f / (float)A_ALIGN;
        float c0 = xs0*inv_a, c1 = xs1*inv_a, c2 = xs2*inv_a;
        float P00 = S00 - c0*rs0, P01 = S01 - c0*rs1, P02 = S02 - c0*rs2;
        float P10 = S10 - c1*rs0, P11 = S11 - c1*rs1, P12 = S12 - c1*rs2;
        float P20 = S20 - c2*rs0, P21 = S21 - c2*rs1, P22 = S22 - c2*rs2;

        float Am[3][3], Vm[3][3];
        Am[0][0] = P00*P00 + P10*P10 + P20*P20;
        Am[0][1] = P00*P01 + P10*P11 + P20*P21;
        Am[0][2] = P00*P02 + P10*P12 + P20*P22;
        Am[1][1] = P01*P01 + P11*P11 + P21*P21;
        Am[1][2] = P01*P02 + P11*P12 + P21*P22;
        Am[2][2] = P02*P02 + P12*P12 + P22*P22;
        Am[1][0]=Am[0][1]; Am[2][0]=Am[0][2]; Am[2][1]=Am[1][2];
        Vm[0][0]=1.f; Vm[0][1]=0.f; Vm[0][2]=0.f;
        Vm[1][0]=0.f; Vm[1][1]=1.f; Vm[1][2]=0.f;
        Vm[2][0]=0.f; Vm[2][1]=0.f; Vm[2][2]=1.f;
#pragma unroll
        for (int sw = 0; sw < 6; ++sw) {
            jrot<0,1,2>(Am, Vm);
            jrot<0,2,1>(Am, Vm);
            jrot<1,2,0>(Am, Vm);
        }

        float l0 = Am[0][0], l1 = Am[1][1], l2 = Am[2][2];
        float v0x=Vm[0][0], v0y=Vm[1][0], v0z=Vm[2][0];
        float v1x=Vm[0][1], v1y=Vm[1][1], v1z=Vm[2][1];
        if (l0 < l1) { float t; t=l0;l0=l1;l1=t;
                       t=v0x;v0x=v1x;v1x=t; t=v0y;v0y=v1y;v1y=t; t=v0z;v0z=v1z;v1z=t; }
        { float v2x=Vm[0][2], v2y=Vm[1][2], v2z=Vm[2][2];
          if (l0 < l2) { float t; t=l0;l0=l2;l2=t;
                         t=v0x;v0x=v2x;v2x=t; t=v0y;v0y=v2y;v2y=t; t=v0z;v0z=v2z;v2z=t; }
          if (l1 < l2) { float t; t=l1;l1=l2;l2=t;
                         t=v1x;v1x=v2x;v2x=t; t=v1y;v1y=v2y;v2y=t; t=v1z;v1z=v2z;v2z=t; }
        }
        float v2x = v0y*v1z - v0z*v1y;
        float v2y = v0z*v1x - v0x*v1z;
        float v2z = v0x*v1y - v0y*v1x;
        float w0x = P00*v0x + P01*v0y + P02*v0z;
        float w0y = P10*v0x + P11*v0y + P12*v0z;
        float w0z = P20*v0x + P21*v0y + P22*v0z;
        float i0 = 1.0f / sqrtf(fmaxf(w0x*w0x+w0y*w0y+w0z*w0z, 1e-30f));
        float u0x=w0x*i0, u0y=w0y*i0, u0z=w0z*i0;
        float w1x = P00*v1x + P01*v1y + P02*v1z;
        float w1y = P10*v1x + P11*v1y + P12*v1z;
        float w1z = P20*v1x + P21*v1y + P22*v1z;
        float d01 = u0x*w1x + u0y*w1y + u0z*w1z;
        w1x -= d01*u0x; w1y -= d01*u0y; w1z -= d01*u0z;
        float i1 = 1.0f / sqrtf(fmaxf(w1x*w1x+w1y*w1y+w1z*w1z, 1e-30f));
        float u1x=w1x*i1, u1y=w1y*i1, u1z=w1z*i1;
        float u2x = u0y*u1z - u0z*u1y;
        float u2y = u0z*u1x - u0x*u1z;
        float u2z = u0x*u1y - u0y*u1x;

        float4* o4 = (float4*)&Pbuf[l * 12];
        o4[0] = make_float4(u0x*v0x + u1x*v1x + u2x*v2x,
                            u0x*v0y + u1x*v1y + u2x*v2y,
                            u0x*v0z + u1x*v1z + u2x*v2z,
                            u0y*v0x + u1y*v1x + u2y*v2x);
        o4[1] = make_float4(u0y*v0y + u1y*v1y + u2y*v2y,
                            u0y*v0z + u1y*v1z + u2y*v2z,
                            u0z*v0x + u1z*v1x + u2z*v2x,
                            u0z*v0y + u1z*v1y + u2z*v2y);
        o4[2] = make_float4(u0z*v0z + u1z*v1z + u2z*v2z, c0, c1, c2);
    }
    __syncthreads();   // Pbuf ready

    // ---------------- Phase 3: register transform + float3 stores -----------
#pragma unroll
    for (int it = 0; it < PPW; ++it) {
        const int rl = w * (PPW * 2) + it * 2 + h;
        const long long brow = bbase + rl;
        if (brow < B) {
            const float4* r4p = (const float4*)&Pbuf[rl * 12]; // bcast/half-wave
            float4 q0 = r4p[0], q1 = r4p[1], q2 = r4p[2];
            float R00=q0.x, R01=q0.y, R02=q0.z, R10=q0.w;
            float R11=q1.x, R12=q1.y, R20=q1.z, R21=q1.w;
            float R22=q2.x, c0=q2.y, c1=q2.z, c2=q2.w;
            {
                float x0 = t0x[it]-c0, x1 = t0y[it]-c1, x2 = t0z[it]-c2;
                float3 y;
                y.x = x0*R00 + x1*R10 + x2*R20;
                y.y = x0*R01 + x1*R11 + x2*R21;
                y.z = x0*R02 + x1*R12 + x2*R22;
                *(float3*)(out + (brow * T_TRAIN + tp) * 3) = y;
            }
            {
                float x0 = t1x[it]-c0, x1 = t1y[it]-c1, x2 = t1z[it]-c2;
                float3 y;
                y.x = x0*R00 + x1*R10 + x2*R20;
                y.y = x0*R01 + x1*R11 + x2*R21;
                y.z = x0*R02 + x1*R12 + x2*R22;
                *(float3*)(out + (brow * T_TRAIN + tp + 32) * 3) = y;
            }
        }
    }
}

extern "C" void kernel_launch(void* const* d_in, const int* in_sizes, int n_in,
                              void* d_out, int out_size, void* d_ws, size_t ws_size,
                              hipStream_t stream)
{
    const float* traj      = (const float*)d_in[0];
    const float* ref_x     = (const float*)d_in[1];
    const int*   align_idx = (const int*)d_in[2];
    const int*   train_idx = (const int*)d_in[3];
    float* out = (float*)d_out;
    int B = in_sizes[0] / (N_ATOMS * 3);

    int nblk = (B + BPBLK - 1) / BPBLK;
    kabsch_block_kernel<<<dim3(nblk), dim3(256), 0, stream>>>(
        traj, ref_x, align_idx, train_idx, out, B);
}